// Round 5
// baseline (167.471 us; speedup 1.0000x reference)
//
#include <hip/hip_runtime.h>
#include <hip/hip_bf16.h>
#include <math.h>

typedef __bf16 bf16_t;
typedef __bf16 bf16x4 __attribute__((ext_vector_type(4)));
typedef __bf16 bf16x8 __attribute__((ext_vector_type(8)));
typedef float  f32x4  __attribute__((ext_vector_type(4)));

static constexpr int Bz = 8, Tt = 2048, Cc = 1024, Dd = 128;
static constexpr int Mm = Bz * Tt;   // 16384
static constexpr int NT64 = Tt / 64; // 32 q-tiles per batch

__device__ __forceinline__ bf16x8 lds_read8(const bf16_t* base, int byte) {
    return *(const bf16x8*)((const char*)base + byte);
}

__device__ __forceinline__ bf16x8 cvt8(float4 a, float4 b) {
    bf16x8 r;
    r[0] = (bf16_t)a.x; r[1] = (bf16_t)a.y; r[2] = (bf16_t)a.z; r[3] = (bf16_t)a.w;
    r[4] = (bf16_t)b.x; r[5] = (bf16_t)b.y; r[6] = (bf16_t)b.z; r[7] = (bf16_t)b.w;
    return r;
}

// ---------------- W f32 -> bf16 concat [384][1024] ----------------
__global__ __launch_bounds__(256) void wcvt_kernel(
    const float* __restrict__ Wq, const float* __restrict__ Wk,
    const float* __restrict__ Wv, bf16_t* __restrict__ Wb)
{
    int g = (blockIdx.x * 256 + threadIdx.x) * 4;   // 384*1024 elems total
    int sel = g >> 17;                               // 131072 per matrix
    const float* W = (sel == 0) ? Wq : (sel == 1) ? Wk : Wv;
    float4 f = *(const float4*)(W + (g & 131071));
    bf16x4 o; o[0] = (bf16_t)f.x; o[1] = (bf16_t)f.y; o[2] = (bf16_t)f.z; o[3] = (bf16_t)f.w;
    *(bf16x4*)(Wb + g) = o;
}

// ---------------- fused QKV projection ----------------
// grid Mm/32 = 512, block 256 (4 waves). Block: rows m0..m0+31, all 384 cols.
// Wave w owns cols [w*96, w*96+96). x-tile staged in LDS (dbuf); B-frags read
// straight from L2-resident bf16 Wb. B-loads for step k+1 issued before the
// barrier so they stay in flight across it.
__global__ __launch_bounds__(256) void qkv_fused(
    const float* __restrict__ x, const bf16_t* __restrict__ Wb,
    const float* __restrict__ bq, const float* __restrict__ bk, const float* __restrict__ bv,
    bf16_t* __restrict__ qo, bf16_t* __restrict__ ko, bf16_t* __restrict__ vTo)
{
    const int m0   = blockIdx.x * 32;
    const int tid  = threadIdx.x;
    const int lane = tid & 63;
    const int w    = tid >> 6;
    const int lo   = lane & 15;
    const int hi   = lane >> 4;

    __shared__ bf16_t Xs[2][32 * 64];   // [m][c] bf16, rows 128B, XOR-swizzled

    f32x4 zero4 = {0.f, 0.f, 0.f, 0.f};
    f32x4 acc[2][6];
    #pragma unroll
    for (int i = 0; i < 2; i++)
        #pragma unroll
        for (int j = 0; j < 6; j++) acc[i][j] = zero4;

    const int xrow = tid >> 3;        // 0..31
    const int xcol = (tid & 7) * 8;   // 8 floats per thread

    float4 fx[2];
    auto load_x = [&](int k0) {
        const float4* s = (const float4*)(x + (size_t)(m0 + xrow) * Cc + k0 + xcol);
        fx[0] = s[0]; fx[1] = s[1];
    };
    auto write_x = [&](int buf) {
        int byte = (xrow * 128 + xcol * 2) ^ ((xrow & 7) << 4);
        *(bf16x8*)((char*)Xs[buf] + byte) = cvt8(fx[0], fx[1]);
    };

    bf16x8 bfr[2][6];
    auto loadB = [&](int k0) {
        #pragma unroll
        for (int kk = 0; kk < 2; kk++)
            #pragma unroll
            for (int j = 0; j < 6; j++)
                bfr[kk][j] = *(const bf16x8*)(Wb + (size_t)(w * 96 + j * 16 + lo) * Cc
                                               + k0 + kk * 32 + hi * 8);
    };

    load_x(0); write_x(0); loadB(0);
    int buf = 0;
    for (int k0 = 0; k0 < Cc; k0 += 64) {
        __syncthreads();
        const bool more = (k0 + 64 < Cc);
        if (more) load_x(k0 + 64);
        bf16x8 af[2][2];
        #pragma unroll
        for (int kk = 0; kk < 2; kk++)
            #pragma unroll
            for (int i = 0; i < 2; i++) {
                int row = i * 16 + lo;
                af[kk][i] = lds_read8(Xs[buf], (row * 128 + kk * 64 + hi * 16) ^ ((row & 7) << 4));
            }
        #pragma unroll
        for (int kk = 0; kk < 2; kk++)
            #pragma unroll
            for (int i = 0; i < 2; i++)
                #pragma unroll
                for (int j = 0; j < 6; j++)
                    acc[i][j] = __builtin_amdgcn_mfma_f32_16x16x32_bf16(af[kk][i], bfr[kk][j], acc[i][j], 0, 0, 0);
        if (more) { loadB(k0 + 64); write_x(buf ^ 1); }  // in flight across barrier
        buf ^= 1;
    }

    #pragma unroll
    for (int j = 0; j < 6; j++) {
        int c = w * 96 + j * 16 + lo;       // 16-col group never crosses a 128 boundary
        int t = c >> 7, d = c & 127;        // t uniform per (wave, j)
        const float* bp = (t == 0) ? bq : (t == 1) ? bk : bv;
        float bb = bp[d];
        #pragma unroll
        for (int i = 0; i < 2; i++)
            #pragma unroll
            for (int r = 0; r < 4; r++) {
                int m = m0 + i * 16 + hi * 4 + r;
                float v = acc[i][j][r] + bb;
                if (t == 0)      qo[(size_t)m * Dd + d] = (bf16_t)v;
                else if (t == 1) ko[(size_t)m * Dd + d] = (bf16_t)v;
                else             vTo[(size_t)d * Mm + m] = (bf16_t)v;
            }
    }
}

// ---------------- causal flash attention (KV-split partials) ----------------
// 1-D grid of 32*nsplit*8 blocks, 256 threads (4 waves x 16 q-rows).
// LPT order (qt descending). Defer-max: skip max-shuffle + accO rescale while
// tile max stays within mrun+8 (P bounded by 2^8; f32 accum safe).
__global__ __launch_bounds__(256, 3) void attn_kernel(
    const bf16_t* __restrict__ qi, const bf16_t* __restrict__ ki,
    const bf16_t* __restrict__ vTi,
    float* __restrict__ Opart, float* __restrict__ Mpart, float* __restrict__ Lpart,
    int nsplit)
{
    const int g   = blockIdx.x;
    const int per = nsplit * 8;
    const int qt  = (NT64 - 1) - g / per;
    const int rem = g % per;
    const int s   = rem >> 3;
    const int b   = rem & 7;
    const int nt  = qt + 1;
    const int t_lo = (s * nt) / nsplit;
    const int t_hi = ((s + 1) * nt) / nsplit;

    const int q0   = qt * 64;
    const int tid  = threadIdx.x;
    const int lane = tid & 63;
    const int w    = tid >> 6;
    const int lo   = lane & 15;
    const int hi   = lane >> 4;

    float* Ob = Opart + ((size_t)s * Mm + (size_t)b * Tt + q0) * Dd;
    float* Mb = Mpart + (size_t)s * Mm + (size_t)b * Tt + q0;
    float* Lb = Lpart + (size_t)s * Mm + (size_t)b * Tt + q0;

    if (t_lo >= t_hi) {  // empty split range: zero partial
        #pragma unroll
        for (int r = 0; r < 4; r++) {
            int row = w * 16 + hi * 4 + r;
            #pragma unroll
            for (int dc = 0; dc < 8; dc++) Ob[(size_t)row * Dd + dc * 16 + lo] = 0.f;
            if (lo == 0) { Mb[row] = -INFINITY; Lb[row] = 0.f; }
        }
        return;
    }

    __shared__ bf16_t Ks[64 * 128];    // [s][d], rows 256B, XOR-swizzled
    __shared__ bf16_t Vs[128 * 64];    // [d][s], rows 128B, XOR-swizzled
    __shared__ bf16_t Ps[4][16 * 64];  // per-wave P [q][s], rows 128B, swizzled

    const float SCALE = 1.4426950408889634f / 32.0f;  // log2(e)/sqrt(C)

    bf16x8 qf[4];
    {
        const bf16_t* qrow = qi + (size_t)(b * Tt + q0 + w * 16 + lo) * Dd;
        #pragma unroll
        for (int kk = 0; kk < 4; kk++)
            qf[kk] = *(const bf16x8*)(qrow + kk * 32 + hi * 8);
    }

    f32x4 zero4 = {0.f, 0.f, 0.f, 0.f};
    f32x4 accO[8];
    #pragma unroll
    for (int i = 0; i < 8; i++) accO[i] = zero4;
    float mrun[4], lrun[4];
    #pragma unroll
    for (int r = 0; r < 4; r++) { mrun[r] = -INFINITY; lrun[r] = 0.f; }

    const int krow = tid >> 2;          // 0..63
    const int kcol = (tid & 3) * 32;
    const int vrow = tid >> 1;          // 0..127
    const int vcol = (tid & 1) * 32;

    bf16x8 kr[4], vr[4];
    auto load_kv = [&](int t) {
        const int kv0 = t * 64;
        const bf16_t* ksrc = ki + (size_t)(b * Tt + kv0 + krow) * Dd + kcol;
        #pragma unroll
        for (int i = 0; i < 4; i++) kr[i] = *(const bf16x8*)(ksrc + i * 8);
        const bf16_t* vsrc = vTi + (size_t)vrow * Mm + (b * Tt + kv0 + vcol);
        #pragma unroll
        for (int i = 0; i < 4; i++) vr[i] = *(const bf16x8*)(vsrc + i * 8);
    };
    auto write_kv = [&]() {
        #pragma unroll
        for (int i = 0; i < 4; i++) {
            int byte = (krow * 256 + (kcol + i * 8) * 2) ^ ((krow & 7) << 4);
            *(bf16x8*)((char*)Ks + byte) = kr[i];
        }
        #pragma unroll
        for (int i = 0; i < 4; i++) {
            int byte = (vrow * 128 + (vcol + i * 8) * 2) ^ ((vrow & 7) << 4);
            *(bf16x8*)((char*)Vs + byte) = vr[i];
        }
    };

    load_kv(t_lo);
    write_kv();
    __syncthreads();

    for (int t = t_lo; t < t_hi; t++) {
        const int kv0 = t * 64;
        const bool more = (t + 1 < t_hi);
        if (more) load_kv(t + 1);          // in flight during compute

        // S = Q K^T : wave's 16 q-rows x 64 s-cols, contract over d=128
        f32x4 accS[4];
        #pragma unroll
        for (int sc = 0; sc < 4; sc++) accS[sc] = zero4;
        #pragma unroll
        for (int kk = 0; kk < 4; kk++)
            #pragma unroll
            for (int sc = 0; sc < 4; sc++) {
                int sr = sc * 16 + lo;
                bf16x8 kf = lds_read8(Ks, (sr * 256 + kk * 64 + hi * 16) ^ ((sr & 7) << 4));
                accS[sc] = __builtin_amdgcn_mfma_f32_16x16x32_bf16(qf[kk], kf, accS[sc], 0, 0, 0);
            }

        // log2-domain scores, diagonal-only mask
        const bool diag = (t == qt);
        float p[4][4];
        #pragma unroll
        for (int sc = 0; sc < 4; sc++) {
            int sg = kv0 + sc * 16 + lo;
            #pragma unroll
            for (int r = 0; r < 4; r++) {
                float vv = accS[sc][r] * SCALE;
                int qg = q0 + w * 16 + hi * 4 + r;
                p[sc][r] = (diag && sg > qg) ? -INFINITY : vv;
            }
        }

        // defer-max test (whole wave; first tile always fails: mrun = -inf)
        bool ok = true;
        float mt[4];
        #pragma unroll
        for (int r = 0; r < 4; r++) {
            mt[r] = fmaxf(fmaxf(p[0][r], p[1][r]), fmaxf(p[2][r], p[3][r]));
            ok = ok && (mt[r] <= mrun[r] + 8.0f);
        }
        if (__all(ok)) {
            #pragma unroll
            for (int r = 0; r < 4; r++) {
                float psum = 0.f;
                #pragma unroll
                for (int sc = 0; sc < 4; sc++) {
                    float pv = exp2f(p[sc][r] - mrun[r]);
                    p[sc][r] = pv;
                    psum += pv;
                }
                psum += __shfl_xor(psum, 1, 64);
                psum += __shfl_xor(psum, 2, 64);
                psum += __shfl_xor(psum, 4, 64);
                psum += __shfl_xor(psum, 8, 64);
                lrun[r] += psum;
            }
        } else {
            #pragma unroll
            for (int r = 0; r < 4; r++) {
                float m = mt[r];
                m = fmaxf(m, __shfl_xor(m, 1, 64));
                m = fmaxf(m, __shfl_xor(m, 2, 64));
                m = fmaxf(m, __shfl_xor(m, 4, 64));
                m = fmaxf(m, __shfl_xor(m, 8, 64));
                float mnew = fmaxf(mrun[r], m);
                float muse = (mnew == -INFINITY) ? 0.f : mnew;
                float alpha = exp2f(mrun[r] - muse);
                mrun[r] = mnew;
                float psum = 0.f;
                #pragma unroll
                for (int sc = 0; sc < 4; sc++) {
                    float pv = exp2f(p[sc][r] - muse);
                    p[sc][r] = pv;
                    psum += pv;
                }
                psum += __shfl_xor(psum, 1, 64);
                psum += __shfl_xor(psum, 2, 64);
                psum += __shfl_xor(psum, 4, 64);
                psum += __shfl_xor(psum, 8, 64);
                lrun[r] = alpha * lrun[r] + psum;
                #pragma unroll
                for (int dc = 0; dc < 8; dc++) accO[dc][r] *= alpha;
            }
        }

        // P (C-layout) -> per-wave LDS -> A-fragment layout
        bf16_t* Pw = Ps[w];
        #pragma unroll
        for (int sc = 0; sc < 4; sc++)
            #pragma unroll
            for (int r = 0; r < 4; r++) {
                int qr = hi * 4 + r;
                int byte = (qr * 128 + (sc * 16 + lo) * 2) ^ ((qr & 7) << 4);
                *(bf16_t*)((char*)Pw + byte) = (bf16_t)p[sc][r];
            }

        // O += P @ V
        #pragma unroll
        for (int kk = 0; kk < 2; kk++) {
            bf16x8 pf = lds_read8(Pw, (lo * 128 + kk * 64 + hi * 16) ^ ((lo & 7) << 4));
            #pragma unroll
            for (int dc = 0; dc < 8; dc++) {
                int dr = dc * 16 + lo;
                bf16x8 vf = lds_read8(Vs, (dr * 128 + kk * 64 + hi * 16) ^ ((dr & 7) << 4));
                accO[dc] = __builtin_amdgcn_mfma_f32_16x16x32_bf16(pf, vf, accO[dc], 0, 0, 0);
            }
        }

        __syncthreads();                    // all waves done reading Ks/Vs
        if (more) write_kv();               // overwrite with prefetched tile
        __syncthreads();
    }

    // unnormalized partial + (m, l)
    #pragma unroll
    for (int r = 0; r < 4; r++) {
        int row = w * 16 + hi * 4 + r;
        float* orow = Ob + (size_t)row * Dd;
        #pragma unroll
        for (int dc = 0; dc < 8; dc++)
            orow[dc * 16 + lo] = accO[dc][r];
        if (lo == 0) { Mb[row] = mrun[r]; Lb[row] = lrun[r]; }
    }
}

// ---------------- split combine + normalize ----------------
__global__ __launch_bounds__(256) void combine_kernel(
    const float* __restrict__ Opart, const float* __restrict__ Mpart,
    const float* __restrict__ Lpart, float* __restrict__ out, int nsplit)
{
    int t   = blockIdx.x * 256 + threadIdx.x;
    int row = t >> 5;
    int dq  = (t & 31) << 2;
    float M = -INFINITY;
    for (int s = 0; s < nsplit; s++)
        M = fmaxf(M, Mpart[(size_t)s * Mm + row]);
    float L = 0.f;
    float o0 = 0.f, o1 = 0.f, o2 = 0.f, o3 = 0.f;
    for (int s = 0; s < nsplit; s++) {
        float ms = Mpart[(size_t)s * Mm + row];
        float ws = (ms == -INFINITY) ? 0.f : exp2f(ms - M);
        L += ws * Lpart[(size_t)s * Mm + row];
        float4 p = *(const float4*)(Opart + ((size_t)s * Mm + row) * Dd + dq);
        o0 += ws * p.x; o1 += ws * p.y; o2 += ws * p.z; o3 += ws * p.w;
    }
    float inv = 1.0f / L;
    float4 r; r.x = o0 * inv; r.y = o1 * inv; r.z = o2 * inv; r.w = o3 * inv;
    *(float4*)(out + (size_t)row * Dd + dq) = r;
}

extern "C" void kernel_launch(void* const* d_in, const int* in_sizes, int n_in,
                              void* d_out, int out_size, void* d_ws, size_t ws_size,
                              hipStream_t stream)
{
    const float* x  = (const float*)d_in[0];
    const float* Wq = (const float*)d_in[1];
    const float* bq = (const float*)d_in[2];
    const float* Wk = (const float*)d_in[3];
    const float* bk = (const float*)d_in[4];
    const float* Wv = (const float*)d_in[5];
    const float* bv = (const float*)d_in[6];
    float* out = (float*)d_out;

    bf16_t* qb = (bf16_t*)d_ws;                 // [M][D] bf16
    bf16_t* kb = qb + (size_t)Mm * Dd;          // [M][D] bf16
    bf16_t* vT = kb + (size_t)Mm * Dd;          // [D][M] bf16
    bf16_t* Wb = vT + (size_t)Mm * Dd;          // [384][1024] bf16
    char* p = (char*)(Wb + (size_t)384 * Cc);

    auto need = [&](int ns) {
        return (size_t)3 * Mm * Dd * 2 + (size_t)384 * Cc * 2
             + (size_t)ns * Mm * Dd * 4 + (size_t)ns * Mm * 8;
    };
    int nsplit = 4;
    while (nsplit > 1 && need(nsplit) > ws_size) nsplit >>= 1;

    float* Opart = (float*)p;                                  // [ns][M][D] f32
    float* Mpart = (float*)(p + (size_t)nsplit * Mm * Dd * 4); // [ns][M]
    float* Lpart = Mpart + (size_t)nsplit * Mm;                // [ns][M]

    wcvt_kernel<<<dim3(384), 256, 0, stream>>>(Wq, Wk, Wv, Wb);
    qkv_fused<<<dim3(Mm / 32), 256, 0, stream>>>(x, Wb, bq, bk, bv, qb, kb, vT);
    attn_kernel<<<dim3(NT64 * nsplit * Bz), 256, 0, stream>>>(qb, kb, vT, Opart, Mpart, Lpart, nsplit);
    combine_kernel<<<dim3(Mm * 32 / 256), 256, 0, stream>>>(Opart, Mpart, Lpart, out, nsplit);
}

// Round 6
// 97.240 us; speedup vs baseline: 1.7222x; 1.7222x over previous
//
#include <hip/hip_runtime.h>
#include <hip/hip_bf16.h>
#include <math.h>

typedef __bf16 bf16_t;
typedef __bf16 bf16x4 __attribute__((ext_vector_type(4)));
typedef __bf16 bf16x8 __attribute__((ext_vector_type(8)));
typedef float  f32x4  __attribute__((ext_vector_type(4)));
typedef float  f32x16 __attribute__((ext_vector_type(16)));
typedef int    v2i    __attribute__((ext_vector_type(2)));

static constexpr int Bz = 8, Tt = 2048, Cc = 1024, Dd = 128;
static constexpr int Mm = Bz * Tt;     // 16384
static constexpr int NT128 = Tt / 128; // 16 q-blocks per batch

__device__ __forceinline__ bf16x8 lds_read8(const char* base, int byte) {
    return *(const bf16x8*)(base + byte);
}

__device__ __forceinline__ bf16x8 cvt8(float4 a, float4 b) {
    bf16x8 r;
    r[0] = (bf16_t)a.x; r[1] = (bf16_t)a.y; r[2] = (bf16_t)a.z; r[3] = (bf16_t)a.w;
    r[4] = (bf16_t)b.x; r[5] = (bf16_t)b.y; r[6] = (bf16_t)b.z; r[7] = (bf16_t)b.w;
    return r;
}

__device__ __forceinline__ unsigned cvtpk(float lo, float hi) {
    unsigned r;
    asm("v_cvt_pk_bf16_f32 %0, %1, %2" : "=v"(r) : "v"(lo), "v"(hi));
    return r;
}

// ---------------- W f32 -> bf16 concat [384][1024] ----------------
__global__ __launch_bounds__(256) void wcvt_kernel(
    const float* __restrict__ Wq, const float* __restrict__ Wk,
    const float* __restrict__ Wv, bf16_t* __restrict__ Wb)
{
    int g = (blockIdx.x * 256 + threadIdx.x) * 4;
    int sel = g >> 17;
    const float* W = (sel == 0) ? Wq : (sel == 1) ? Wk : Wv;
    float4 f = *(const float4*)(W + (g & 131071));
    bf16x4 o; o[0] = (bf16_t)f.x; o[1] = (bf16_t)f.y; o[2] = (bf16_t)f.z; o[3] = (bf16_t)f.w;
    *(bf16x4*)(Wb + g) = o;
}

// ---------------- fused QKV projection (unchanged from r5) ----------------
__global__ __launch_bounds__(256) void qkv_fused(
    const float* __restrict__ x, const bf16_t* __restrict__ Wb,
    const float* __restrict__ bq, const float* __restrict__ bk, const float* __restrict__ bv,
    bf16_t* __restrict__ qo, bf16_t* __restrict__ ko, bf16_t* __restrict__ vTo)
{
    const int m0   = blockIdx.x * 32;
    const int tid  = threadIdx.x;
    const int lane = tid & 63;
    const int w    = tid >> 6;
    const int lo   = lane & 15;
    const int hi   = lane >> 4;

    __shared__ bf16_t Xs[2][32 * 64];

    f32x4 zero4 = {0.f, 0.f, 0.f, 0.f};
    f32x4 acc[2][6];
    #pragma unroll
    for (int i = 0; i < 2; i++)
        #pragma unroll
        for (int j = 0; j < 6; j++) acc[i][j] = zero4;

    const int xrow = tid >> 3;
    const int xcol = (tid & 7) * 8;

    float4 fx[2];
    auto load_x = [&](int k0) {
        const float4* s = (const float4*)(x + (size_t)(m0 + xrow) * Cc + k0 + xcol);
        fx[0] = s[0]; fx[1] = s[1];
    };
    auto write_x = [&](int buf) {
        int byte = (xrow * 128 + xcol * 2) ^ ((xrow & 7) << 4);
        *(bf16x8*)((char*)Xs[buf] + byte) = cvt8(fx[0], fx[1]);
    };

    bf16x8 bfr[2][6];
    auto loadB = [&](int k0) {
        #pragma unroll
        for (int kk = 0; kk < 2; kk++)
            #pragma unroll
            for (int j = 0; j < 6; j++)
                bfr[kk][j] = *(const bf16x8*)(Wb + (size_t)(w * 96 + j * 16 + lo) * Cc
                                               + k0 + kk * 32 + hi * 8);
    };

    load_x(0); write_x(0); loadB(0);
    int buf = 0;
    for (int k0 = 0; k0 < Cc; k0 += 64) {
        __syncthreads();
        const bool more = (k0 + 64 < Cc);
        if (more) load_x(k0 + 64);
        bf16x8 af[2][2];
        #pragma unroll
        for (int kk = 0; kk < 2; kk++)
            #pragma unroll
            for (int i = 0; i < 2; i++) {
                int row = i * 16 + lo;
                af[kk][i] = lds_read8((char*)Xs[buf], (row * 128 + kk * 64 + hi * 16) ^ ((row & 7) << 4));
            }
        #pragma unroll
        for (int kk = 0; kk < 2; kk++)
            #pragma unroll
            for (int i = 0; i < 2; i++)
                #pragma unroll
                for (int j = 0; j < 6; j++)
                    acc[i][j] = __builtin_amdgcn_mfma_f32_16x16x32_bf16(af[kk][i], bfr[kk][j], acc[i][j], 0, 0, 0);
        if (more) { loadB(k0 + 64); write_x(buf ^ 1); }
        buf ^= 1;
    }

    #pragma unroll
    for (int j = 0; j < 6; j++) {
        int c = w * 96 + j * 16 + lo;
        int t = c >> 7, d = c & 127;
        const float* bp = (t == 0) ? bq : (t == 1) ? bk : bv;
        float bb = bp[d];
        #pragma unroll
        for (int i = 0; i < 2; i++)
            #pragma unroll
            for (int r = 0; r < 4; r++) {
                int m = m0 + i * 16 + hi * 4 + r;
                float v = acc[i][j][r] + bb;
                if (t == 0)      qo[(size_t)m * Dd + d] = (bf16_t)v;
                else if (t == 1) ko[(size_t)m * Dd + d] = (bf16_t)v;
                else             vTo[(size_t)d * Mm + m] = (bf16_t)v;
            }
    }
}

// ---------------- causal flash attention, swapped-operand 32x32 ----------------
// 512 blocks (16 qt x 8 b x nsplit), 256 threads = 4 waves x 32 q-rows.
// S = K Q^T (lane owns q = lane&31, all kv rows in-register);
// O^T = V^T P^T (lane's acc cols = its own q -> lane-local softmax/rescale).
__global__ __launch_bounds__(256, 2) void attn_kernel(
    const bf16_t* __restrict__ qi, const bf16_t* __restrict__ ki,
    const bf16_t* __restrict__ vTi,
    float* __restrict__ Opart, float* __restrict__ Mpart, float* __restrict__ Lpart,
    int nsplit)
{
    const int g   = blockIdx.x;
    const int per = nsplit * 8;
    const int qt  = (NT128 - 1) - g / per;   // LPT: big qt first
    const int rem = g % per;
    const int s   = rem >> 3;
    const int b   = rem & 7;
    const int nt  = 2 * qt + 2;
    const int t_lo = (s * nt) / nsplit;
    const int t_hi = ((s + 1) * nt) / nsplit;

    const int q0   = qt * 128;
    const int tid  = threadIdx.x;
    const int lane = tid & 63;
    const int w    = tid >> 6;
    const int rq   = lane & 31;   // this lane's q within the wave tile
    const int dh   = lane >> 5;   // half-wave: k-offset selector

    float* Ob = Opart + ((size_t)s * Mm + (size_t)b * Tt + q0) * Dd;
    float* Mb = Mpart + (size_t)s * Mm + (size_t)b * Tt + q0;
    float* Lb = Lpart + (size_t)s * Mm + (size_t)b * Tt + q0;

    if (t_lo >= t_hi) {   // empty split: zero 128x128 partial
        float4 z = {0.f, 0.f, 0.f, 0.f};
        #pragma unroll
        for (int i = 0; i < 16; i++)
            ((float4*)Ob)[i * 256 + tid] = z;
        if (tid < 128) { Mb[tid] = -INFINITY; Lb[tid] = 0.f; }
        return;
    }

    __shared__ __align__(16) char smem[65536];
    // Ks tiles: [64 kv][128 d] bf16, 256B rows, ^((row&15)<<4) swizzle, dbuf at 0/16KB
    // VsT tiles: [64][128] bf16 packed as row=d&63, col=(d>>6)*64+kv, dbuf at 32/48KB

    const float SCALE = 1.4426950408889634f / 32.0f;   // log2(e)/sqrt(C)
    const int qg = q0 + w * 32 + rq;                   // lane's q (batch-local)
    const int qwmax = q0 + w * 32 + 31;

    // Q fragments (B-operand of K*Q^T): qf[ks] = q[qg][16ks + 8dh .. +8]
    bf16x8 qf[8];
    {
        const bf16_t* qrow = qi + (size_t)(b * Tt + qg) * Dd;
        #pragma unroll
        for (int ks = 0; ks < 8; ks++)
            qf[ks] = *(const bf16x8*)(qrow + ks * 16 + dh * 8);
    }

    f32x16 accO[4];
    #pragma unroll
    for (int ds = 0; ds < 4; ds++)
        #pragma unroll
        for (int e = 0; e < 16; e++) accO[ds][e] = 0.f;
    float mrun = -INFINITY, lrun = 0.f;

    // staging assignment (tid-based, all waves)
    const int krow = tid >> 2;            // 0..63
    const int kcol = (tid & 3) * 32;      // d
    const int vrow = tid >> 1;            // 0..127 = d
    const int vcol = (tid & 1) * 32;      // kv

    bf16x8 kr[4], vr[4];
    auto load_kv = [&](int t) {
        const int kv0 = t * 64;
        const bf16_t* ksrc = ki + (size_t)(b * Tt + kv0 + krow) * Dd + kcol;
        #pragma unroll
        for (int i = 0; i < 4; i++) kr[i] = *(const bf16x8*)(ksrc + i * 8);
        const bf16_t* vsrc = vTi + (size_t)vrow * Mm + (b * Tt + kv0 + vcol);
        #pragma unroll
        for (int i = 0; i < 4; i++) vr[i] = *(const bf16x8*)(vsrc + i * 8);
    };
    auto write_kv = [&](int buf) {
        char* Ksb = smem + buf * 16384;
        char* Vsb = smem + 32768 + buf * 16384;
        #pragma unroll
        for (int i = 0; i < 4; i++) {
            int byte = (krow * 256 + (kcol + i * 8) * 2) ^ ((krow & 15) << 4);
            *(bf16x8*)(Ksb + byte) = kr[i];
        }
        const int vlr = vrow & 63;
        const int vlc = (vrow >> 6) * 64 + vcol;
        #pragma unroll
        for (int i = 0; i < 4; i++) {
            int byte = (vlr * 256 + (vlc + i * 8) * 2) ^ ((vlr & 15) << 4);
            *(bf16x8*)(Vsb + byte) = vr[i];
        }
    };

    load_kv(t_lo);
    write_kv(0);
    int buf = 0;

    for (int t = t_lo; t < t_hi; t++) {
        const int kv0 = t * 64;
        const bool more = (t + 1 < t_hi);
        __syncthreads();
        if (more) load_kv(t + 1);          // in flight across compute

        if (kv0 <= qwmax) {                // not fully masked for this wave
            const char* Ksb = smem + buf * 16384;
            const char* Vsb = smem + 32768 + buf * 16384;

            // S = K Q^T : two 32-row kv subtiles, chain over d
            f32x16 accS0, accS1;
            #pragma unroll
            for (int e = 0; e < 16; e++) { accS0[e] = 0.f; accS1[e] = 0.f; }
            #pragma unroll
            for (int ks = 0; ks < 8; ks++) {
                int colb = (ks * 16 + dh * 8) * 2;
                bf16x8 kf0 = lds_read8(Ksb, ((rq)      * 256 + colb) ^ ((rq & 15) << 4));
                bf16x8 kf1 = lds_read8(Ksb, ((32 + rq) * 256 + colb) ^ ((rq & 15) << 4));
                accS0 = __builtin_amdgcn_mfma_f32_32x32x16_bf16(kf0, qf[ks], accS0, 0, 0, 0);
                accS1 = __builtin_amdgcn_mfma_f32_32x32x16_bf16(kf1, qf[ks], accS1, 0, 0, 0);
            }

            // lane-local scores: pl[e] has k = kv0 + 8*(e>>2)+(e&3)+4dh (+32 for upper)
            float pl[32];
            #pragma unroll
            for (int e = 0; e < 16; e++) {
                pl[e]      = accS0[e] * SCALE;
                pl[16 + e] = accS1[e] * SCALE;
            }
            if (kv0 + 63 > qg) {           // diagonal tile: mask k > q
                #pragma unroll
                for (int e = 0; e < 16; e++) {
                    int kg = kv0 + 8 * (e >> 2) + (e & 3) + 4 * dh;
                    if (kg > qg)      pl[e]      = -INFINITY;
                    if (kg + 32 > qg) pl[16 + e] = -INFINITY;
                }
            }

            // online softmax, fully lane-local (+1 shfl to merge partner half)
            float mt = pl[0];
            #pragma unroll
            for (int e = 1; e < 32; e++) mt = fmaxf(mt, pl[e]);
            mt = fmaxf(mt, __shfl_xor(mt, 32, 64));
            float mnew = fmaxf(mrun, mt);
            float muse = (mnew == -INFINITY) ? 0.f : mnew;
            float alpha = exp2f(mrun - muse);
            mrun = mnew;
            float ps = 0.f;
            #pragma unroll
            for (int e = 0; e < 32; e++) {
                float pv = exp2f(pl[e] - muse);
                pl[e] = pv;
                ps += pv;
            }
            lrun = alpha * lrun + ps;
            #pragma unroll
            for (int ds = 0; ds < 4; ds++)
                #pragma unroll
                for (int e = 0; e < 16; e++) accO[ds][e] *= alpha;

            // P^T fragments in-register: cvt_pk pairs + permlane32_swap (T12)
            unsigned u0[8], u1[8];
            #pragma unroll
            for (int gg = 0; gg < 8; gg++) {
                u0[gg] = cvtpk(pl[4 * gg + 0], pl[4 * gg + 1]);
                u1[gg] = cvtpk(pl[4 * gg + 2], pl[4 * gg + 3]);
            }
            bf16x8 pa[4];
            #pragma unroll
            for (int ks = 0; ks < 4; ks++) {
                v2i rA = __builtin_amdgcn_permlane32_swap((int)u0[2 * ks], (int)u0[2 * ks + 1], false, false);
                v2i rB = __builtin_amdgcn_permlane32_swap((int)u1[2 * ks], (int)u1[2 * ks + 1], false, false);
                union { unsigned wd[4]; bf16x8 v; } pu;
                pu.wd[0] = (unsigned)rA[0];   // k-offsets 0,1   (from h'=0)
                pu.wd[1] = (unsigned)rB[0];   // k-offsets 2,3
                pu.wd[2] = (unsigned)rA[1];   // k-offsets 4,5   (from h'=1)
                pu.wd[3] = (unsigned)rB[1];   // k-offsets 6,7
                pa[ks] = pu.v;
            }

            // O^T += V^T P^T
            #pragma unroll
            for (int ds = 0; ds < 4; ds++) {
                int row  = (ds & 1) * 32 + rq;
                int cb   = (ds >> 1) * 64;
                #pragma unroll
                for (int ks = 0; ks < 4; ks++) {
                    int colb = (cb + ks * 16 + dh * 8) * 2;
                    bf16x8 vf = lds_read8(Vsb, (row * 256 + colb) ^ ((row & 15) << 4));
                    accO[ds] = __builtin_amdgcn_mfma_f32_32x32x16_bf16(vf, pa[ks], accO[ds], 0, 0, 0);
                }
            }
        }

        __syncthreads();
        if (more) write_kv(buf ^ 1);
        buf ^= 1;
    }

    __syncthreads();   // done with K/V LDS; reuse as per-wave transpose slabs

    lrun += __shfl_xor(lrun, 32, 64);      // partner holds the other 32 k's

    // epilogue: transpose O^T -> row-major partial via 8KB per-wave LDS slab
    char* slab = smem + w * 8192;          // 32 rows x 256B, same XOR swizzle
    const int orow = q0 + w * 32 + rq;     // wait: row read below uses rq as q
    #pragma unroll
    for (int half = 0; half < 2; half++) {
        #pragma unroll
        for (int dsl = 0; dsl < 2; dsl++) {
            #pragma unroll
            for (int e = 0; e < 16; e++) {
                int d = 8 * (e >> 2) + (e & 3) + 4 * dh + 32 * dsl;   // 0..63
                int byte = (rq * 256 + d * 4) ^ ((rq & 15) << 4);
                *(float*)(slab + byte) = accO[half * 2 + dsl][e];
            }
        }
        __builtin_amdgcn_s_waitcnt(0);     // lgkmcnt drain before readback
        #pragma unroll
        for (int i = 0; i < 8; i++) {
            int dd = 32 * dh + 4 * i;
            int byte = (rq * 256 + dd * 4) ^ ((rq & 15) << 4);
            float4 val = *(float4*)(slab + byte);
            *(float4*)(Ob + (size_t)(w * 32 + rq) * Dd + half * 64 + dd) = val;
        }
        __builtin_amdgcn_s_waitcnt(0);
    }

    if (lane < 32) {
        Mb[w * 32 + rq] = mrun;
        Lb[w * 32 + rq] = lrun;
    }
    (void)orow;
}

// ---------------- split combine + normalize ----------------
__global__ __launch_bounds__(256) void combine_kernel(
    const float* __restrict__ Opart, const float* __restrict__ Mpart,
    const float* __restrict__ Lpart, float* __restrict__ out, int nsplit)
{
    int t   = blockIdx.x * 256 + threadIdx.x;
    int row = t >> 5;
    int dq  = (t & 31) << 2;
    float M = -INFINITY;
    for (int s = 0; s < nsplit; s++)
        M = fmaxf(M, Mpart[(size_t)s * Mm + row]);
    float L = 0.f;
    float o0 = 0.f, o1 = 0.f, o2 = 0.f, o3 = 0.f;
    for (int s = 0; s < nsplit; s++) {
        float ms = Mpart[(size_t)s * Mm + row];
        float ws = (ms == -INFINITY) ? 0.f : exp2f(ms - M);
        L += ws * Lpart[(size_t)s * Mm + row];
        float4 p = *(const float4*)(Opart + ((size_t)s * Mm + row) * Dd + dq);
        o0 += ws * p.x; o1 += ws * p.y; o2 += ws * p.z; o3 += ws * p.w;
    }
    float inv = 1.0f / L;
    float4 r; r.x = o0 * inv; r.y = o1 * inv; r.z = o2 * inv; r.w = o3 * inv;
    *(float4*)(out + (size_t)row * Dd + dq) = r;
}

extern "C" void kernel_launch(void* const* d_in, const int* in_sizes, int n_in,
                              void* d_out, int out_size, void* d_ws, size_t ws_size,
                              hipStream_t stream)
{
    const float* x  = (const float*)d_in[0];
    const float* Wq = (const float*)d_in[1];
    const float* bq = (const float*)d_in[2];
    const float* Wk = (const float*)d_in[3];
    const float* bk = (const float*)d_in[4];
    const float* Wv = (const float*)d_in[5];
    const float* bv = (const float*)d_in[6];
    float* out = (float*)d_out;

    bf16_t* qb = (bf16_t*)d_ws;                 // [M][D] bf16
    bf16_t* kb = qb + (size_t)Mm * Dd;          // [M][D] bf16
    bf16_t* vT = kb + (size_t)Mm * Dd;          // [D][M] bf16
    bf16_t* Wb = vT + (size_t)Mm * Dd;          // [384][1024] bf16
    char* p = (char*)(Wb + (size_t)384 * Cc);

    auto need = [&](int ns) {
        return (size_t)3 * Mm * Dd * 2 + (size_t)384 * Cc * 2
             + (size_t)ns * Mm * Dd * 4 + (size_t)ns * Mm * 8;
    };
    int nsplit = 4;
    while (nsplit > 1 && need(nsplit) > ws_size) nsplit >>= 1;

    float* Opart = (float*)p;                                  // [ns][M][D] f32
    float* Mpart = (float*)(p + (size_t)nsplit * Mm * Dd * 4); // [ns][M]
    float* Lpart = Mpart + (size_t)nsplit * Mm;                // [ns][M]

    wcvt_kernel<<<dim3(384), 256, 0, stream>>>(Wq, Wk, Wv, Wb);
    qkv_fused<<<dim3(Mm / 32), 256, 0, stream>>>(x, Wb, bq, bk, bv, qb, kb, vT);
    attn_kernel<<<dim3(NT128 * nsplit * Bz), 256, 0, stream>>>(qb, kb, vT, Opart, Mpart, Lpart, nsplit);
    combine_kernel<<<dim3(Mm * 32 / 256), 256, 0, stream>>>(Opart, Mpart, Lpart, out, nsplit);
}

// Round 7
// 70.399 us; speedup vs baseline: 2.3789x; 1.3813x over previous
//
#include <hip/hip_runtime.h>
#include <hip/hip_bf16.h>
#include <math.h>

typedef __bf16 bf16_t;
typedef __bf16 bf16x4 __attribute__((ext_vector_type(4)));
typedef __bf16 bf16x8 __attribute__((ext_vector_type(8)));
typedef float  f32x4  __attribute__((ext_vector_type(4)));
typedef float  f32x16 __attribute__((ext_vector_type(16)));
typedef int    v2i    __attribute__((ext_vector_type(2)));

static constexpr int Bz = 8, Tt = 2048, Cc = 1024, Dd = 128;
static constexpr int Mm = Bz * Tt;     // 16384
static constexpr int NT128 = Tt / 128; // 16 q-blocks per batch

__device__ __forceinline__ bf16x8 lds_read8(const char* base, int byte) {
    return *(const bf16x8*)(base + byte);
}

__device__ __forceinline__ bf16x8 cvt8(float4 a, float4 b) {
    bf16x8 r;
    r[0] = (bf16_t)a.x; r[1] = (bf16_t)a.y; r[2] = (bf16_t)a.z; r[3] = (bf16_t)a.w;
    r[4] = (bf16_t)b.x; r[5] = (bf16_t)b.y; r[6] = (bf16_t)b.z; r[7] = (bf16_t)b.w;
    return r;
}

__device__ __forceinline__ unsigned cvtpk(float lo, float hi) {
    unsigned r;
    asm("v_cvt_pk_bf16_f32 %0, %1, %2" : "=v"(r) : "v"(lo), "v"(hi));
    return r;
}

// ---------------- W f32 -> bf16, packed to MFMA-fragment-linear order -------
// element (n 0..383, k 0..1023) -> Wp[(((ktile*24+ng)*2+kk)*4+hi)*16+lo)*8+e]
// ktile=k>>6, kk=(k>>5)&1, hi=(k>>3)&3, e=k&7, ng=n>>4, lo=n&15.
// A wave's fragment load (fixed ng,kk) = 64 lanes x 8 bf16 contiguous = 1 KB.
__global__ __launch_bounds__(256) void wcvt_kernel(
    const float* __restrict__ Wq, const float* __restrict__ Wk,
    const float* __restrict__ Wv, bf16_t* __restrict__ Wp)
{
    int g = (blockIdx.x * 256 + threadIdx.x) * 4;   // 4 consecutive k of one n
    int n = g >> 10;
    int k = g & 1023;
    int sel = n >> 7;                                // 128 rows per matrix
    const float* W = (sel == 0) ? Wq : (sel == 1) ? Wk : Wv;
    float4 f = *(const float4*)(W + (size_t)(n & 127) * 1024 + k);
    bf16x4 o; o[0] = (bf16_t)f.x; o[1] = (bf16_t)f.y; o[2] = (bf16_t)f.z; o[3] = (bf16_t)f.w;
    int ktile = k >> 6, kk = (k >> 5) & 1, hi = (k >> 3) & 3, e = k & 7;
    int addr = (((((ktile * 24 + (n >> 4)) * 2 + kk) * 4 + hi) * 16 + (n & 15)) * 8) + e;
    *(bf16x4*)(Wp + addr) = o;
}

// ---------------- fused QKV projection ----------------
// grid Mm/32 = 512, block 256 (4 waves). Block: rows m0..m0+31, all 384 cols.
// Wave w owns cols [w*96, w*96+96). x-tile LDS double-buffered; W fragments
// register-double-buffered (bfrA/bfrB) and loaded fully-coalesced from packed
// Wp one full K-step ahead of use.
__global__ __launch_bounds__(256) void qkv_fused(
    const float* __restrict__ x, const bf16_t* __restrict__ Wp,
    const float* __restrict__ bq, const float* __restrict__ bk, const float* __restrict__ bv,
    bf16_t* __restrict__ qo, bf16_t* __restrict__ ko, bf16_t* __restrict__ vTo)
{
    const int m0   = blockIdx.x * 32;
    const int tid  = threadIdx.x;
    const int lane = tid & 63;
    const int w    = tid >> 6;
    const int lo   = lane & 15;
    const int hi   = lane >> 4;

    __shared__ bf16_t Xs[2][32 * 64];

    f32x4 zero4 = {0.f, 0.f, 0.f, 0.f};
    f32x4 acc[2][6];
    #pragma unroll
    for (int i = 0; i < 2; i++)
        #pragma unroll
        for (int j = 0; j < 6; j++) acc[i][j] = zero4;

    const int xrow = tid >> 3;
    const int xcol = (tid & 7) * 8;

    float4 fx[2];
    auto load_x = [&](int k0) {
        const float4* s = (const float4*)(x + (size_t)(m0 + xrow) * Cc + k0 + xcol);
        fx[0] = s[0]; fx[1] = s[1];
    };
    auto write_x = [&](int buf) {
        int byte = (xrow * 128 + xcol * 2) ^ ((xrow & 7) << 4);
        *(bf16x8*)((char*)Xs[buf] + byte) = cvt8(fx[0], fx[1]);
    };

    bf16x8 bfrA[2][6], bfrB[2][6];
    auto loadB = [&](bf16x8 (&dst)[2][6], int k0) {
        const bf16_t* base = Wp + (size_t)(k0 >> 6) * (24 * 2 * 64 * 8) + lane * 8;
        #pragma unroll
        for (int j = 0; j < 6; j++)
            #pragma unroll
            for (int kk = 0; kk < 2; kk++)
                dst[kk][j] = *(const bf16x8*)(base + (((w * 6 + j) * 2 + kk) * 64) * 8);
    };
    auto mfma_step = [&](const bf16x8 (&bfr)[2][6], int buf) {
        #pragma unroll
        for (int kk = 0; kk < 2; kk++) {
            bf16x8 af0 = lds_read8((char*)Xs[buf], ((lo)      * 128 + kk * 64 + hi * 16) ^ ((lo & 7) << 4));
            bf16x8 af1 = lds_read8((char*)Xs[buf], ((16 + lo) * 128 + kk * 64 + hi * 16) ^ ((lo & 7) << 4));
            #pragma unroll
            for (int j = 0; j < 6; j++)
                acc[0][j] = __builtin_amdgcn_mfma_f32_16x16x32_bf16(af0, bfr[kk][j], acc[0][j], 0, 0, 0);
            #pragma unroll
            for (int j = 0; j < 6; j++)
                acc[1][j] = __builtin_amdgcn_mfma_f32_16x16x32_bf16(af1, bfr[kk][j], acc[1][j], 0, 0, 0);
        }
    };

    // prologue: tile0 staged, W frags for steps 0 and 1 in flight
    load_x(0); write_x(0); loadB(bfrA, 0);
    __syncthreads();
    load_x(64); loadB(bfrB, 64);

    for (int k0 = 0; k0 < Cc; k0 += 128) {
        const bool m2 = (k0 + 128 < Cc);
        // even step: k = k0 (Xs[0], bfrA)
        mfma_step(bfrA, 0);
        write_x(1);                        // x-tile k0+64 -> Xs[1]
        if (m2) load_x(k0 + 128);
        __syncthreads();
        if (m2) loadB(bfrA, k0 + 128);     // lands during odd step
        // odd step: k = k0+64 (Xs[1], bfrB)
        mfma_step(bfrB, 1);
        if (m2) { write_x(0); load_x(k0 + 192); }
        __syncthreads();
        if (k0 + 192 < Cc) loadB(bfrB, k0 + 192);
    }

    #pragma unroll
    for (int j = 0; j < 6; j++) {
        int c = w * 96 + j * 16 + lo;
        int t = c >> 7, d = c & 127;
        const float* bp = (t == 0) ? bq : (t == 1) ? bk : bv;
        float bb = bp[d];
        #pragma unroll
        for (int i = 0; i < 2; i++)
            #pragma unroll
            for (int r = 0; r < 4; r++) {
                int m = m0 + i * 16 + hi * 4 + r;
                float v = acc[i][j][r] + bb;
                if (t == 0)      qo[(size_t)m * Dd + d] = (bf16_t)v;
                else if (t == 1) ko[(size_t)m * Dd + d] = (bf16_t)v;
                else             vTo[(size_t)d * Mm + m] = (bf16_t)v;
            }
    }
}

// ---------------- causal flash attention, swapped-operand 32x32 ----------------
// (unchanged from round 6)
__global__ __launch_bounds__(256, 2) void attn_kernel(
    const bf16_t* __restrict__ qi, const bf16_t* __restrict__ ki,
    const bf16_t* __restrict__ vTi,
    float* __restrict__ Opart, float* __restrict__ Mpart, float* __restrict__ Lpart,
    int nsplit)
{
    const int g   = blockIdx.x;
    const int per = nsplit * 8;
    const int qt  = (NT128 - 1) - g / per;
    const int rem = g % per;
    const int s   = rem >> 3;
    const int b   = rem & 7;
    const int nt  = 2 * qt + 2;
    const int t_lo = (s * nt) / nsplit;
    const int t_hi = ((s + 1) * nt) / nsplit;

    const int q0   = qt * 128;
    const int tid  = threadIdx.x;
    const int lane = tid & 63;
    const int w    = tid >> 6;
    const int rq   = lane & 31;
    const int dh   = lane >> 5;

    float* Ob = Opart + ((size_t)s * Mm + (size_t)b * Tt + q0) * Dd;
    float* Mb = Mpart + (size_t)s * Mm + (size_t)b * Tt + q0;
    float* Lb = Lpart + (size_t)s * Mm + (size_t)b * Tt + q0;

    if (t_lo >= t_hi) {
        float4 z = {0.f, 0.f, 0.f, 0.f};
        #pragma unroll
        for (int i = 0; i < 16; i++)
            ((float4*)Ob)[i * 256 + tid] = z;
        if (tid < 128) { Mb[tid] = -INFINITY; Lb[tid] = 0.f; }
        return;
    }

    __shared__ __align__(16) char smem[65536];

    const float SCALE = 1.4426950408889634f / 32.0f;
    const int qg = q0 + w * 32 + rq;
    const int qwmax = q0 + w * 32 + 31;

    bf16x8 qf[8];
    {
        const bf16_t* qrow = qi + (size_t)(b * Tt + qg) * Dd;
        #pragma unroll
        for (int ks = 0; ks < 8; ks++)
            qf[ks] = *(const bf16x8*)(qrow + ks * 16 + dh * 8);
    }

    f32x16 accO[4];
    #pragma unroll
    for (int ds = 0; ds < 4; ds++)
        #pragma unroll
        for (int e = 0; e < 16; e++) accO[ds][e] = 0.f;
    float mrun = -INFINITY, lrun = 0.f;

    const int krow = tid >> 2;
    const int kcol = (tid & 3) * 32;
    const int vrow = tid >> 1;
    const int vcol = (tid & 1) * 32;

    bf16x8 kr[4], vr[4];
    auto load_kv = [&](int t) {
        const int kv0 = t * 64;
        const bf16_t* ksrc = ki + (size_t)(b * Tt + kv0 + krow) * Dd + kcol;
        #pragma unroll
        for (int i = 0; i < 4; i++) kr[i] = *(const bf16x8*)(ksrc + i * 8);
        const bf16_t* vsrc = vTi + (size_t)vrow * Mm + (b * Tt + kv0 + vcol);
        #pragma unroll
        for (int i = 0; i < 4; i++) vr[i] = *(const bf16x8*)(vsrc + i * 8);
    };
    auto write_kv = [&](int buf) {
        char* Ksb = smem + buf * 16384;
        char* Vsb = smem + 32768 + buf * 16384;
        #pragma unroll
        for (int i = 0; i < 4; i++) {
            int byte = (krow * 256 + (kcol + i * 8) * 2) ^ ((krow & 15) << 4);
            *(bf16x8*)(Ksb + byte) = kr[i];
        }
        const int vlr = vrow & 63;
        const int vlc = (vrow >> 6) * 64 + vcol;
        #pragma unroll
        for (int i = 0; i < 4; i++) {
            int byte = (vlr * 256 + (vlc + i * 8) * 2) ^ ((vlr & 15) << 4);
            *(bf16x8*)(Vsb + byte) = vr[i];
        }
    };

    load_kv(t_lo);
    write_kv(0);
    int buf = 0;

    for (int t = t_lo; t < t_hi; t++) {
        const int kv0 = t * 64;
        const bool more = (t + 1 < t_hi);
        __syncthreads();
        if (more) load_kv(t + 1);

        if (kv0 <= qwmax) {
            const char* Ksb = smem + buf * 16384;
            const char* Vsb = smem + 32768 + buf * 16384;

            f32x16 accS0, accS1;
            #pragma unroll
            for (int e = 0; e < 16; e++) { accS0[e] = 0.f; accS1[e] = 0.f; }
            #pragma unroll
            for (int ks = 0; ks < 8; ks++) {
                int colb = (ks * 16 + dh * 8) * 2;
                bf16x8 kf0 = lds_read8(Ksb, ((rq)      * 256 + colb) ^ ((rq & 15) << 4));
                bf16x8 kf1 = lds_read8(Ksb, ((32 + rq) * 256 + colb) ^ ((rq & 15) << 4));
                accS0 = __builtin_amdgcn_mfma_f32_32x32x16_bf16(kf0, qf[ks], accS0, 0, 0, 0);
                accS1 = __builtin_amdgcn_mfma_f32_32x32x16_bf16(kf1, qf[ks], accS1, 0, 0, 0);
            }

            float pl[32];
            #pragma unroll
            for (int e = 0; e < 16; e++) {
                pl[e]      = accS0[e] * SCALE;
                pl[16 + e] = accS1[e] * SCALE;
            }
            if (kv0 + 63 > qg) {
                #pragma unroll
                for (int e = 0; e < 16; e++) {
                    int kg = kv0 + 8 * (e >> 2) + (e & 3) + 4 * dh;
                    if (kg > qg)      pl[e]      = -INFINITY;
                    if (kg + 32 > qg) pl[16 + e] = -INFINITY;
                }
            }

            float mt = pl[0];
            #pragma unroll
            for (int e = 1; e < 32; e++) mt = fmaxf(mt, pl[e]);
            mt = fmaxf(mt, __shfl_xor(mt, 32, 64));
            float mnew = fmaxf(mrun, mt);
            float muse = (mnew == -INFINITY) ? 0.f : mnew;
            float alpha = exp2f(mrun - muse);
            mrun = mnew;
            float ps = 0.f;
            #pragma unroll
            for (int e = 0; e < 32; e++) {
                float pv = exp2f(pl[e] - muse);
                pl[e] = pv;
                ps += pv;
            }
            lrun = alpha * lrun + ps;
            #pragma unroll
            for (int ds = 0; ds < 4; ds++)
                #pragma unroll
                for (int e = 0; e < 16; e++) accO[ds][e] *= alpha;

            unsigned u0[8], u1[8];
            #pragma unroll
            for (int gg = 0; gg < 8; gg++) {
                u0[gg] = cvtpk(pl[4 * gg + 0], pl[4 * gg + 1]);
                u1[gg] = cvtpk(pl[4 * gg + 2], pl[4 * gg + 3]);
            }
            bf16x8 pa[4];
            #pragma unroll
            for (int ks = 0; ks < 4; ks++) {
                v2i rA = __builtin_amdgcn_permlane32_swap((int)u0[2 * ks], (int)u0[2 * ks + 1], false, false);
                v2i rB = __builtin_amdgcn_permlane32_swap((int)u1[2 * ks], (int)u1[2 * ks + 1], false, false);
                union { unsigned wd[4]; bf16x8 v; } pu;
                pu.wd[0] = (unsigned)rA[0];
                pu.wd[1] = (unsigned)rB[0];
                pu.wd[2] = (unsigned)rA[1];
                pu.wd[3] = (unsigned)rB[1];
                pa[ks] = pu.v;
            }

            #pragma unroll
            for (int ds = 0; ds < 4; ds++) {
                int row  = (ds & 1) * 32 + rq;
                int cb   = (ds >> 1) * 64;
                #pragma unroll
                for (int ks = 0; ks < 4; ks++) {
                    int colb = (cb + ks * 16 + dh * 8) * 2;
                    bf16x8 vf = lds_read8(Vsb, (row * 256 + colb) ^ ((row & 15) << 4));
                    accO[ds] = __builtin_amdgcn_mfma_f32_32x32x16_bf16(vf, pa[ks], accO[ds], 0, 0, 0);
                }
            }
        }

        __syncthreads();
        if (more) write_kv(buf ^ 1);
        buf ^= 1;
    }

    __syncthreads();

    lrun += __shfl_xor(lrun, 32, 64);

    char* slab = smem + w * 8192;
    #pragma unroll
    for (int half = 0; half < 2; half++) {
        #pragma unroll
        for (int dsl = 0; dsl < 2; dsl++) {
            #pragma unroll
            for (int e = 0; e < 16; e++) {
                int d = 8 * (e >> 2) + (e & 3) + 4 * dh + 32 * dsl;
                int byte = (rq * 256 + d * 4) ^ ((rq & 15) << 4);
                *(float*)(slab + byte) = accO[half * 2 + dsl][e];
            }
        }
        __builtin_amdgcn_s_waitcnt(0);
        #pragma unroll
        for (int i = 0; i < 8; i++) {
            int dd = 32 * dh + 4 * i;
            int byte = (rq * 256 + dd * 4) ^ ((rq & 15) << 4);
            float4 val = *(float4*)(slab + byte);
            *(float4*)(Ob + (size_t)(w * 32 + rq) * Dd + half * 64 + dd) = val;
        }
        __builtin_amdgcn_s_waitcnt(0);
    }

    if (lane < 32) {
        Mb[w * 32 + rq] = mrun;
        Lb[w * 32 + rq] = lrun;
    }
}

// ---------------- split combine + normalize ----------------
__global__ __launch_bounds__(256) void combine_kernel(
    const float* __restrict__ Opart, const float* __restrict__ Mpart,
    const float* __restrict__ Lpart, float* __restrict__ out, int nsplit)
{
    int t   = blockIdx.x * 256 + threadIdx.x;
    int row = t >> 5;
    int dq  = (t & 31) << 2;
    float M = -INFINITY;
    for (int s = 0; s < nsplit; s++)
        M = fmaxf(M, Mpart[(size_t)s * Mm + row]);
    float L = 0.f;
    float o0 = 0.f, o1 = 0.f, o2 = 0.f, o3 = 0.f;
    for (int s = 0; s < nsplit; s++) {
        float ms = Mpart[(size_t)s * Mm + row];
        float ws = (ms == -INFINITY) ? 0.f : exp2f(ms - M);
        L += ws * Lpart[(size_t)s * Mm + row];
        float4 p = *(const float4*)(Opart + ((size_t)s * Mm + row) * Dd + dq);
        o0 += ws * p.x; o1 += ws * p.y; o2 += ws * p.z; o3 += ws * p.w;
    }
    float inv = 1.0f / L;
    float4 r; r.x = o0 * inv; r.y = o1 * inv; r.z = o2 * inv; r.w = o3 * inv;
    *(float4*)(out + (size_t)row * Dd + dq) = r;
}

extern "C" void kernel_launch(void* const* d_in, const int* in_sizes, int n_in,
                              void* d_out, int out_size, void* d_ws, size_t ws_size,
                              hipStream_t stream)
{
    const float* x  = (const float*)d_in[0];
    const float* Wq = (const float*)d_in[1];
    const float* bq = (const float*)d_in[2];
    const float* Wk = (const float*)d_in[3];
    const float* bk = (const float*)d_in[4];
    const float* Wv = (const float*)d_in[5];
    const float* bv = (const float*)d_in[6];
    float* out = (float*)d_out;

    bf16_t* qb = (bf16_t*)d_ws;                 // [M][D] bf16
    bf16_t* kb = qb + (size_t)Mm * Dd;          // [M][D] bf16
    bf16_t* vT = kb + (size_t)Mm * Dd;          // [D][M] bf16
    bf16_t* Wp = vT + (size_t)Mm * Dd;          // packed [384*1024] bf16
    char* p = (char*)(Wp + (size_t)384 * Cc);

    auto need = [&](int ns) {
        return (size_t)3 * Mm * Dd * 2 + (size_t)384 * Cc * 2
             + (size_t)ns * Mm * Dd * 4 + (size_t)ns * Mm * 8;
    };
    int nsplit = 4;
    while (nsplit > 1 && need(nsplit) > ws_size) nsplit >>= 1;

    float* Opart = (float*)p;                                  // [ns][M][D] f32
    float* Mpart = (float*)(p + (size_t)nsplit * Mm * Dd * 4); // [ns][M]
    float* Lpart = Mpart + (size_t)nsplit * Mm;                // [ns][M]

    wcvt_kernel<<<dim3(384), 256, 0, stream>>>(Wq, Wk, Wv, Wp);
    qkv_fused<<<dim3(Mm / 32), 256, 0, stream>>>(x, Wp, bq, bk, bv, qb, kb, vT);
    attn_kernel<<<dim3(NT128 * nsplit * Bz), 256, 0, stream>>>(qb, kb, vT, Opart, Mpart, Lpart, nsplit);
    combine_kernel<<<dim3(Mm * 32 / 256), 256, 0, stream>>>(Opart, Mpart, Lpart, out, nsplit);
}